// Round 1
// baseline (1618.340 us; speedup 1.0000x reference)
//
#include <hip/hip_runtime.h>
#include <math.h>

// Problem constants (B=2, S=2048, D=1024, H=16, hd=64)
constexpr int B = 2, S = 2048, D = 1024, H = 16, HD = 64;
constexpr size_t QSZ = (size_t)B * H * S * HD;  // 4194304 floats per Q/K/V
constexpr size_t BHS = (size_t)B * H * S;       // 65536
constexpr float SCALE = 0.125f;                 // 1/sqrt(64), folded into Q
constexpr float EPS = 1e-5f;

// ---------------------------------------------------------------------------
// Kernel 1: QKV projection.  qkv[i,j] = dot(x[i,:], W[j,:]) + b[j]
// Scatter to Q/K/V in [B,H,S,HD] layout; Q pre-scaled by 1/8.
// Tiles: 64x64 output, BK=32.  LDS k-major, pad 68.
// ---------------------------------------------------------------------------
__global__ __launch_bounds__(256) void k_qkv(const float* __restrict__ x,
                                             const float* __restrict__ W,
                                             const float* __restrict__ bias,
                                             float* __restrict__ Qo,
                                             float* __restrict__ Ko,
                                             float* __restrict__ Vo) {
  __shared__ float As[32 * 68];
  __shared__ float Bs[32 * 68];
  const int tid = threadIdx.x;
  const int tx = tid & 15, ty = tid >> 4;
  const int row0 = blockIdx.y * 64;
  const int col0 = blockIdx.x * 64;
  float acc[4][4] = {};

  const int lm = tid >> 3;          // 0..31
  const int lk4 = (tid & 7) * 4;    // 0,4,..,28

  for (int k0 = 0; k0 < D; k0 += 32) {
#pragma unroll
    for (int p = 0; p < 2; ++p) {
      const int mm = lm + p * 32;
      const float4 va = *reinterpret_cast<const float4*>(
          &x[(size_t)(row0 + mm) * D + k0 + lk4]);
      As[(lk4 + 0) * 68 + mm] = va.x;
      As[(lk4 + 1) * 68 + mm] = va.y;
      As[(lk4 + 2) * 68 + mm] = va.z;
      As[(lk4 + 3) * 68 + mm] = va.w;
      const float4 vb = *reinterpret_cast<const float4*>(
          &W[(size_t)(col0 + mm) * D + k0 + lk4]);
      Bs[(lk4 + 0) * 68 + mm] = vb.x;
      Bs[(lk4 + 1) * 68 + mm] = vb.y;
      Bs[(lk4 + 2) * 68 + mm] = vb.z;
      Bs[(lk4 + 3) * 68 + mm] = vb.w;
    }
    __syncthreads();
#pragma unroll 8
    for (int kk = 0; kk < 32; ++kk) {
      const float4 ra = *reinterpret_cast<const float4*>(&As[kk * 68 + ty * 4]);
      const float4 rb = *reinterpret_cast<const float4*>(&Bs[kk * 68 + tx * 4]);
      const float a4[4] = {ra.x, ra.y, ra.z, ra.w};
      const float b4[4] = {rb.x, rb.y, rb.z, rb.w};
#pragma unroll
      for (int r = 0; r < 4; ++r)
#pragma unroll
        for (int c = 0; c < 4; ++c) acc[r][c] = fmaf(a4[r], b4[c], acc[r][c]);
    }
    __syncthreads();
  }

  const int part = col0 >> 10;           // 0=Q,1=K,2=V
  const int h = (col0 & 1023) >> 6;      // head (uniform per block)
  float* dst = (part == 0) ? Qo : (part == 1) ? Ko : Vo;
  const float sc = (part == 0) ? SCALE : 1.0f;
  float bx[4];
#pragma unroll
  for (int c = 0; c < 4; ++c) bx[c] = bias[col0 + tx * 4 + c];
#pragma unroll
  for (int r = 0; r < 4; ++r) {
    const int i = row0 + ty * 4 + r;
    const int bb = i >> 11, ss = i & 2047;
    float4 o;
    o.x = (acc[r][0] + bx[0]) * sc;
    o.y = (acc[r][1] + bx[1]) * sc;
    o.z = (acc[r][2] + bx[2]) * sc;
    o.w = (acc[r][3] + bx[3]) * sc;
    *reinterpret_cast<float4*>(
        &dst[(((size_t)bb * H + h) * S + ss) * HD + tx * 4]) = o;
  }
}

// ---------------------------------------------------------------------------
// Loader helpers for 64x64 tiles of [rows, HD] matrices.
// ---------------------------------------------------------------------------
__device__ __forceinline__ void load64_T(const float* __restrict__ src, int r0,
                                         float* __restrict__ dst, int ldd,
                                         int tid) {
  // dst[d * ldd + row] = src[(r0+row)*HD + d]
  const int r = tid >> 4;
  const int d4 = (tid & 15) * 4;
#pragma unroll
  for (int p = 0; p < 4; ++p) {
    const int rr = r + p * 16;
    const float4 v =
        *reinterpret_cast<const float4*>(&src[(size_t)(r0 + rr) * HD + d4]);
    dst[(d4 + 0) * ldd + rr] = v.x;
    dst[(d4 + 1) * ldd + rr] = v.y;
    dst[(d4 + 2) * ldd + rr] = v.z;
    dst[(d4 + 3) * ldd + rr] = v.w;
  }
}

__device__ __forceinline__ void load64_N(const float* __restrict__ src, int r0,
                                         float* __restrict__ dst, int ldd,
                                         int tid) {
  // dst[row * ldd + d] = src[(r0+row)*HD + d]
  const int r = tid >> 4;
  const int d4 = (tid & 15) * 4;
#pragma unroll
  for (int p = 0; p < 4; ++p) {
    const int rr = r + p * 16;
    const float4 v =
        *reinterpret_cast<const float4*>(&src[(size_t)(r0 + rr) * HD + d4]);
    *reinterpret_cast<float4*>(&dst[rr * ldd + d4]) = v;
  }
}

// ---------------------------------------------------------------------------
// Kernel 2: per-row softmax stats (m = rowmax, l = sum exp(s-m)).
// One block per (b, h, 64 q-rows).  Q is pre-scaled, s = q.k
// ---------------------------------------------------------------------------
__global__ __launch_bounds__(256) void k_ml(const float* __restrict__ Qi,
                                            const float* __restrict__ Ki,
                                            float* __restrict__ mo,
                                            float* __restrict__ lo) {
  __shared__ float Qs[64 * 64];  // [d][row] (one-time load; write conflicts ok)
  __shared__ float Ks[64 * 68];  // [d][kc]
  const int tid = threadIdx.x;
  const int tx = tid & 15, ty = tid >> 4;
  const int q0 = blockIdx.x * 64;
  const int h = blockIdx.y, b = blockIdx.z;
  const float* Qb = Qi + ((size_t)b * H + h) * S * HD;
  const float* Kb = Ki + ((size_t)b * H + h) * S * HD;

  load64_T(Qb, q0, Qs, 64, tid);

  float mcur[4] = {-INFINITY, -INFINITY, -INFINITY, -INFINITY};
  float lcur[4] = {0.f, 0.f, 0.f, 0.f};

  for (int k0 = 0; k0 < S; k0 += 64) {
    load64_T(Kb, k0, Ks, 68, tid);
    __syncthreads();
    float sacc[4][4] = {};
#pragma unroll 8
    for (int dd = 0; dd < 64; ++dd) {
      const float4 ra = *reinterpret_cast<const float4*>(&Qs[dd * 64 + ty * 4]);
      const float4 rb = *reinterpret_cast<const float4*>(&Ks[dd * 68 + tx * 4]);
      const float a4[4] = {ra.x, ra.y, ra.z, ra.w};
      const float b4[4] = {rb.x, rb.y, rb.z, rb.w};
#pragma unroll
      for (int r = 0; r < 4; ++r)
#pragma unroll
        for (int c = 0; c < 4; ++c)
          sacc[r][c] = fmaf(a4[r], b4[c], sacc[r][c]);
    }
#pragma unroll
    for (int r = 0; r < 4; ++r) {
      const float mx = fmaxf(fmaxf(sacc[r][0], sacc[r][1]),
                             fmaxf(sacc[r][2], sacc[r][3]));
      const float nm = fmaxf(mcur[r], mx);
      const float add = __expf(sacc[r][0] - nm) + __expf(sacc[r][1] - nm) +
                        __expf(sacc[r][2] - nm) + __expf(sacc[r][3] - nm);
      lcur[r] = lcur[r] * __expf(mcur[r] - nm) + add;
      mcur[r] = nm;
    }
    __syncthreads();
  }
  // reduce across the 16 tx lanes (contiguous within a wave)
#pragma unroll
  for (int r = 0; r < 4; ++r) {
#pragma unroll
    for (int off = 1; off < 16; off <<= 1) {
      const float om = __shfl_xor(mcur[r], off);
      const float ol = __shfl_xor(lcur[r], off);
      const float nm = fmaxf(mcur[r], om);
      lcur[r] = lcur[r] * __expf(mcur[r] - nm) + ol * __expf(om - nm);
      mcur[r] = nm;
    }
  }
  if (tx == 0) {
#pragma unroll
    for (int r = 0; r < 4; ++r) {
      const size_t idx = ((size_t)b * H + h) * S + q0 + ty * 4 + r;
      mo[idx] = mcur[r];
      lo[idx] = lcur[r];
    }
  }
}

// ---------------------------------------------------------------------------
// Kernel 3: ctx = softmax(QK^T) @ V using precomputed (m,l).
// LDS: Qs [d][row], union Ks[d][kc]/Ps[row][kc] (pad 68), Vs [kc][d].
// ---------------------------------------------------------------------------
__global__ __launch_bounds__(256) void k_ctx(const float* __restrict__ Qi,
                                             const float* __restrict__ Ki,
                                             const float* __restrict__ Vi,
                                             const float* __restrict__ mi,
                                             const float* __restrict__ li,
                                             float* __restrict__ ctx) {
  __shared__ float Qs[64 * 64];
  __shared__ float KPs[64 * 68];  // Ks then reused as Ps
  __shared__ float Vs[64 * 64];
  const int tid = threadIdx.x;
  const int tx = tid & 15, ty = tid >> 4;
  const int q0 = blockIdx.x * 64;
  const int h = blockIdx.y, b = blockIdx.z;
  const float* Qb = Qi + ((size_t)b * H + h) * S * HD;
  const float* Kb = Ki + ((size_t)b * H + h) * S * HD;
  const float* Vb = Vi + ((size_t)b * H + h) * S * HD;

  load64_T(Qb, q0, Qs, 64, tid);

  float mrow[4], linv[4];
#pragma unroll
  for (int r = 0; r < 4; ++r) {
    const size_t idx = ((size_t)b * H + h) * S + q0 + ty * 4 + r;
    mrow[r] = mi[idx];
    linv[r] = 1.0f / li[idx];
  }
  float cacc[4][4] = {};

  for (int k0 = 0; k0 < S; k0 += 64) {
    load64_T(Kb, k0, KPs, 68, tid);
    load64_N(Vb, k0, Vs, 64, tid);
    __syncthreads();
    float sacc[4][4] = {};
#pragma unroll 8
    for (int dd = 0; dd < 64; ++dd) {
      const float4 ra = *reinterpret_cast<const float4*>(&Qs[dd * 64 + ty * 4]);
      const float4 rb = *reinterpret_cast<const float4*>(&KPs[dd * 68 + tx * 4]);
      const float a4[4] = {ra.x, ra.y, ra.z, ra.w};
      const float b4[4] = {rb.x, rb.y, rb.z, rb.w};
#pragma unroll
      for (int r = 0; r < 4; ++r)
#pragma unroll
        for (int c = 0; c < 4; ++c)
          sacc[r][c] = fmaf(a4[r], b4[c], sacc[r][c]);
    }
    __syncthreads();  // everyone done reading Ks; reuse as Ps
#pragma unroll
    for (int r = 0; r < 4; ++r) {
      float4 pv;
      pv.x = __expf(sacc[r][0] - mrow[r]);
      pv.y = __expf(sacc[r][1] - mrow[r]);
      pv.z = __expf(sacc[r][2] - mrow[r]);
      pv.w = __expf(sacc[r][3] - mrow[r]);
      *reinterpret_cast<float4*>(&KPs[(ty * 4 + r) * 68 + tx * 4]) = pv;
    }
    __syncthreads();
#pragma unroll 4
    for (int kc = 0; kc < 64; ++kc) {
      float pa[4];
#pragma unroll
      for (int r = 0; r < 4; ++r) pa[r] = KPs[(ty * 4 + r) * 68 + kc];
      const float4 rv = *reinterpret_cast<const float4*>(&Vs[kc * 64 + tx * 4]);
      const float v4[4] = {rv.x, rv.y, rv.z, rv.w};
#pragma unroll
      for (int r = 0; r < 4; ++r)
#pragma unroll
        for (int c = 0; c < 4; ++c)
          cacc[r][c] = fmaf(pa[r], v4[c], cacc[r][c]);
    }
    __syncthreads();
  }
#pragma unroll
  for (int r = 0; r < 4; ++r) {
    const int row = q0 + ty * 4 + r;
    float4 o;
    o.x = cacc[r][0] * linv[r];
    o.y = cacc[r][1] * linv[r];
    o.z = cacc[r][2] * linv[r];
    o.w = cacc[r][3] * linv[r];
    *reinterpret_cast<float4*>(
        &ctx[((size_t)b * S + row) * D + h * HD + tx * 4]) = o;
  }
}

// ---------------------------------------------------------------------------
// Kernel 4: attn_weights mean over heads.  One block per (b, q-tile, k-tile);
// loops all 16 heads, writes the [64,64] averaged block once.
// ---------------------------------------------------------------------------
__global__ __launch_bounds__(256) void k_weights(const float* __restrict__ Qi,
                                                 const float* __restrict__ Ki,
                                                 const float* __restrict__ mi,
                                                 const float* __restrict__ li,
                                                 float* __restrict__ attn) {
  __shared__ float Qs[64 * 68];
  __shared__ float Ks[64 * 68];
  const int tid = threadIdx.x;
  const int tx = tid & 15, ty = tid >> 4;
  const int k0 = blockIdx.x * 64;
  const int q0 = blockIdx.y * 64;
  const int b = blockIdx.z;
  float wacc[4][4] = {};

  for (int h = 0; h < H; ++h) {
    const float* Qb = Qi + ((size_t)b * H + h) * S * HD;
    const float* Kb = Ki + ((size_t)b * H + h) * S * HD;
    load64_T(Qb, q0, Qs, 68, tid);
    load64_T(Kb, k0, Ks, 68, tid);
    __syncthreads();
    float sacc[4][4] = {};
#pragma unroll 8
    for (int dd = 0; dd < 64; ++dd) {
      const float4 ra = *reinterpret_cast<const float4*>(&Qs[dd * 68 + ty * 4]);
      const float4 rb = *reinterpret_cast<const float4*>(&Ks[dd * 68 + tx * 4]);
      const float a4[4] = {ra.x, ra.y, ra.z, ra.w};
      const float b4[4] = {rb.x, rb.y, rb.z, rb.w};
#pragma unroll
      for (int r = 0; r < 4; ++r)
#pragma unroll
        for (int c = 0; c < 4; ++c)
          sacc[r][c] = fmaf(a4[r], b4[c], sacc[r][c]);
    }
#pragma unroll
    for (int r = 0; r < 4; ++r) {
      const size_t idx = ((size_t)b * H + h) * S + q0 + ty * 4 + r;
      const float m = mi[idx];
      const float lv = 1.0f / li[idx];
#pragma unroll
      for (int c = 0; c < 4; ++c)
        wacc[r][c] = fmaf(__expf(sacc[r][c] - m), lv, wacc[r][c]);
    }
    __syncthreads();
  }
  const float inv_h = 1.0f / (float)H;
#pragma unroll
  for (int r = 0; r < 4; ++r) {
    const int row = q0 + ty * 4 + r;
    float4 o;
    o.x = wacc[r][0] * inv_h;
    o.y = wacc[r][1] * inv_h;
    o.z = wacc[r][2] * inv_h;
    o.w = wacc[r][3] * inv_h;
    *reinterpret_cast<float4*>(&attn[((size_t)b * S + row) * S + k0 + tx * 4]) =
        o;
  }
}

// ---------------------------------------------------------------------------
// Kernel 5a: out projection + bias + residual.  y = ctx @ Wout^T + b + x
// ---------------------------------------------------------------------------
__global__ __launch_bounds__(256) void k_oproj(const float* __restrict__ ctx,
                                               const float* __restrict__ W,
                                               const float* __restrict__ bias,
                                               const float* __restrict__ x,
                                               float* __restrict__ y) {
  __shared__ float As[32 * 68];
  __shared__ float Bs[32 * 68];
  const int tid = threadIdx.x;
  const int tx = tid & 15, ty = tid >> 4;
  const int row0 = blockIdx.y * 64;
  const int col0 = blockIdx.x * 64;
  float acc[4][4] = {};

  const int lm = tid >> 3;
  const int lk4 = (tid & 7) * 4;

  for (int k0 = 0; k0 < D; k0 += 32) {
#pragma unroll
    for (int p = 0; p < 2; ++p) {
      const int mm = lm + p * 32;
      const float4 va = *reinterpret_cast<const float4*>(
          &ctx[(size_t)(row0 + mm) * D + k0 + lk4]);
      As[(lk4 + 0) * 68 + mm] = va.x;
      As[(lk4 + 1) * 68 + mm] = va.y;
      As[(lk4 + 2) * 68 + mm] = va.z;
      As[(lk4 + 3) * 68 + mm] = va.w;
      const float4 vb = *reinterpret_cast<const float4*>(
          &W[(size_t)(col0 + mm) * D + k0 + lk4]);
      Bs[(lk4 + 0) * 68 + mm] = vb.x;
      Bs[(lk4 + 1) * 68 + mm] = vb.y;
      Bs[(lk4 + 2) * 68 + mm] = vb.z;
      Bs[(lk4 + 3) * 68 + mm] = vb.w;
    }
    __syncthreads();
#pragma unroll 8
    for (int kk = 0; kk < 32; ++kk) {
      const float4 ra = *reinterpret_cast<const float4*>(&As[kk * 68 + ty * 4]);
      const float4 rb = *reinterpret_cast<const float4*>(&Bs[kk * 68 + tx * 4]);
      const float a4[4] = {ra.x, ra.y, ra.z, ra.w};
      const float b4[4] = {rb.x, rb.y, rb.z, rb.w};
#pragma unroll
      for (int r = 0; r < 4; ++r)
#pragma unroll
        for (int c = 0; c < 4; ++c) acc[r][c] = fmaf(a4[r], b4[c], acc[r][c]);
    }
    __syncthreads();
  }
  float bx[4];
#pragma unroll
  for (int c = 0; c < 4; ++c) bx[c] = bias[col0 + tx * 4 + c];
#pragma unroll
  for (int r = 0; r < 4; ++r) {
    const int i = row0 + ty * 4 + r;
    const size_t off = (size_t)i * D + col0 + tx * 4;
    const float4 xr = *reinterpret_cast<const float4*>(&x[off]);
    float4 o;
    o.x = acc[r][0] + bx[0] + xr.x;
    o.y = acc[r][1] + bx[1] + xr.y;
    o.z = acc[r][2] + bx[2] + xr.z;
    o.w = acc[r][3] + bx[3] + xr.w;
    *reinterpret_cast<float4*>(&y[off]) = o;
  }
}

// ---------------------------------------------------------------------------
// Kernel 5b: in-place LayerNorm over last dim (one block per row).
// ---------------------------------------------------------------------------
__global__ __launch_bounds__(256) void k_ln(float* __restrict__ y,
                                            const float* __restrict__ gamma,
                                            const float* __restrict__ beta) {
  const int row = blockIdx.x;
  const int tid = threadIdx.x;
  const float4 v = *reinterpret_cast<const float4*>(&y[(size_t)row * D + tid * 4]);
  float s = v.x + v.y + v.z + v.w;
  float sq = v.x * v.x + v.y * v.y + v.z * v.z + v.w * v.w;
#pragma unroll
  for (int off = 32; off > 0; off >>= 1) {
    s += __shfl_down(s, off);
    sq += __shfl_down(sq, off);
  }
  __shared__ float sm[8];
  const int wid = tid >> 6, lane = tid & 63;
  if (lane == 0) {
    sm[wid] = s;
    sm[4 + wid] = sq;
  }
  __syncthreads();
  s = sm[0] + sm[1] + sm[2] + sm[3];
  sq = sm[4] + sm[5] + sm[6] + sm[7];
  const float mu = s * (1.0f / D);
  const float var = sq * (1.0f / D) - mu * mu;
  const float rstd = rsqrtf(var + EPS);
  const float4 g = *reinterpret_cast<const float4*>(&gamma[tid * 4]);
  const float4 bt = *reinterpret_cast<const float4*>(&beta[tid * 4]);
  float4 o;
  o.x = (v.x - mu) * rstd * g.x + bt.x;
  o.y = (v.y - mu) * rstd * g.y + bt.y;
  o.z = (v.z - mu) * rstd * g.z + bt.z;
  o.w = (v.w - mu) * rstd * g.w + bt.w;
  *reinterpret_cast<float4*>(&y[(size_t)row * D + tid * 4]) = o;
}

// ---------------------------------------------------------------------------
extern "C" void kernel_launch(void* const* d_in, const int* in_sizes, int n_in,
                              void* d_out, int out_size, void* d_ws,
                              size_t ws_size, hipStream_t stream) {
  const float* x = (const float*)d_in[0];
  const float* inW = (const float*)d_in[1];
  const float* inB = (const float*)d_in[2];
  const float* outW = (const float*)d_in[3];
  const float* outB = (const float*)d_in[4];
  const float* gamma = (const float*)d_in[5];
  const float* beta = (const float*)d_in[6];

  float* out = (float*)d_out;                    // [B,S,D]
  float* attn = out + (size_t)B * S * D;         // [B,S,S]

  float* ws = (float*)d_ws;
  float* Q = ws;
  float* K = ws + QSZ;
  float* V = ws + 2 * QSZ;
  float* m = ws + 3 * QSZ;
  float* l = m + BHS;
  // ctx temporarily lives in the attn-weights region of d_out (written by
  // k_weights only AFTER k_oproj has consumed ctx).
  float* ctx = attn;

  k_qkv<<<dim3(48, 64), 256, 0, stream>>>(x, inW, inB, Q, K, V);
  k_ml<<<dim3(32, 16, 2), 256, 0, stream>>>(Q, K, m, l);
  k_ctx<<<dim3(32, 16, 2), 256, 0, stream>>>(Q, K, V, m, l, ctx);
  k_oproj<<<dim3(16, 64), 256, 0, stream>>>(ctx, outW, outB, x, out);
  k_weights<<<dim3(32, 32, 2), 256, 0, stream>>>(Q, K, m, l, attn);
  k_ln<<<4096, 256, 0, stream>>>(out, gamma, beta);
}

// Round 2
// 558.373 us; speedup vs baseline: 2.8983x; 2.8983x over previous
//
#include <hip/hip_runtime.h>
#include <math.h>

constexpr int B = 2, S = 2048, D = 1024, H = 16, HD = 64;
constexpr int T = B * S;  // 4096 tokens
constexpr float EPS = 1e-5f;

typedef float f32x4 __attribute__((ext_vector_type(4)));
typedef __bf16 bf16x8 __attribute__((ext_vector_type(8)));

struct alignas(16) u4 { unsigned x, y, z, w; };
struct alignas(8) u2 { unsigned x, y; };

__device__ __forceinline__ unsigned short f2bf(float f) {
  unsigned u = __float_as_uint(f);
  u += 0x7fffu + ((u >> 16) & 1u);
  return (unsigned short)(u >> 16);
}
__device__ __forceinline__ float bf2f(unsigned short h) {
  return __uint_as_float(((unsigned)h) << 16);
}
__device__ __forceinline__ f32x4 MM(bf16x8 a, bf16x8 b, f32x4 c) {
  return __builtin_amdgcn_mfma_f32_16x16x32_bf16(a, b, c, 0, 0, 0);
}
union U16x8 { u4 q; bf16x8 b; };

// Load one MFMA operand fragment (8 contiguous k-elems) from a swizzled
// 64x64 bf16 LDS tile. Tile layout: 16B chunk (r,c) stored at
// r*128 + ((c ^ (r&7))*16).
__device__ __forceinline__ bf16x8 ld_frag(const unsigned short* lds, int row,
                                          int chunk) {
  U16x8 u;
  u.q = *(const u4*)((const char*)lds + row * 128 +
                     (((chunk) ^ (row & 7)) * 16));
  return u.b;
}

// Stage a 64-row x 64-u16 tile from global into swizzled LDS. 256 threads.
__device__ __forceinline__ void stage64(const unsigned short* __restrict__ src,
                                        size_t off, int rstride,
                                        unsigned short* lds, int tid) {
#pragma unroll
  for (int p = 0; p < 2; ++p) {
    const int idx = tid + p * 256;
    const int r = idx >> 3, c = idx & 7;
    u4 v = *(const u4*)(src + off + (size_t)r * rstride + c * 8);
    *(u4*)((char*)lds + r * 128 + ((c ^ (r & 7)) * 16)) = v;
  }
}

// ---------------------------------------------------------------------------
// Split fp32 -> bf16 hi + bf16 lo
// ---------------------------------------------------------------------------
__global__ __launch_bounds__(256) void k_split(const float* __restrict__ src,
                                               unsigned short* __restrict__ hi,
                                               unsigned short* __restrict__ lo,
                                               int n4) {
  const int i = blockIdx.x * 256 + threadIdx.x;
  if (i >= n4) return;
  const float4 v = ((const float4*)src)[i];
  const unsigned short h0 = f2bf(v.x), h1 = f2bf(v.y), h2 = f2bf(v.z),
                       h3 = f2bf(v.w);
  u2 hh, ll;
  hh.x = (unsigned)h0 | ((unsigned)h1 << 16);
  hh.y = (unsigned)h2 | ((unsigned)h3 << 16);
  ll.x = (unsigned)f2bf(v.x - bf2f(h0)) | ((unsigned)f2bf(v.y - bf2f(h1)) << 16);
  ll.y = (unsigned)f2bf(v.z - bf2f(h2)) | ((unsigned)f2bf(v.w - bf2f(h3)) << 16);
  ((u2*)hi)[i] = hh;
  ((u2*)lo)[i] = ll;
}

// ---------------------------------------------------------------------------
// QKV projection (MFMA, 3-term split). Output: Q,K split bf16 [B,H,S,HD]
// (Q pre-scaled by 1/8), V split bf16 TRANSPOSED [B,H,HD,S].
// ---------------------------------------------------------------------------
__global__ __launch_bounds__(256) void k_qkv(
    const unsigned short* __restrict__ xh, const unsigned short* __restrict__ xl,
    const unsigned short* __restrict__ wh, const unsigned short* __restrict__ wl,
    const float* __restrict__ bias,
    unsigned short* __restrict__ Qh, unsigned short* __restrict__ Ql,
    unsigned short* __restrict__ Kh, unsigned short* __restrict__ Kl,
    unsigned short* __restrict__ Vh, unsigned short* __restrict__ Vl) {
  __shared__ unsigned short Ah[4096], Al[4096], Bh[4096], Bl[4096];
  const int tid = threadIdx.x;
  const int w = tid >> 6, lane = tid & 63;
  const int j = lane & 15, g = lane >> 4;
  const int row0 = blockIdx.y * 64;  // token tile
  const int col0 = blockIdx.x * 64;  // of 3072
  const f32x4 z4 = {0.f, 0.f, 0.f, 0.f};
  f32x4 acc[4] = {z4, z4, z4, z4};

  for (int k0 = 0; k0 < D; k0 += 64) {
    __syncthreads();
    stage64(xh, (size_t)row0 * D + k0, D, Ah, tid);
    stage64(xl, (size_t)row0 * D + k0, D, Al, tid);
    stage64(wh, (size_t)col0 * D + k0, D, Bh, tid);
    stage64(wl, (size_t)col0 * D + k0, D, Bl, tid);
    __syncthreads();
#pragma unroll
    for (int kk = 0; kk < 2; ++kk) {
      const int arow = 16 * w + j;
      const bf16x8 ah = ld_frag(Ah, arow, kk * 4 + g);
      const bf16x8 al = ld_frag(Al, arow, kk * 4 + g);
#pragma unroll
      for (int nf = 0; nf < 4; ++nf) {
        const bf16x8 bh = ld_frag(Bh, 16 * nf + j, kk * 4 + g);
        const bf16x8 bl = ld_frag(Bl, 16 * nf + j, kk * 4 + g);
        acc[nf] = MM(ah, bh, acc[nf]);
        acc[nf] = MM(ah, bl, acc[nf]);
        acc[nf] = MM(al, bh, acc[nf]);
      }
    }
  }

  const int part = col0 >> 10;  // 0=Q 1=K 2=V
  const int h = (col0 & 1023) >> 6;
  if (part < 2) {
    const float qsc = (part == 0) ? 0.125f : 1.0f;
    unsigned short* dh = (part == 0) ? Qh : Kh;
    unsigned short* dl = (part == 0) ? Ql : Kl;
#pragma unroll
    for (int nf = 0; nf < 4; ++nf) {
      const int hd = 16 * nf + j;
      const float bv = bias[col0 + hd];
#pragma unroll
      for (int r = 0; r < 4; ++r) {
        const int tok = row0 + 16 * w + 4 * g + r;
        const int bb = tok >> 11, ss = tok & 2047;
        const float v = (acc[nf][r] + bv) * qsc;
        const unsigned short hh = f2bf(v);
        const size_t o = (((size_t)bb * H + h) * S + ss) * HD + hd;
        dh[o] = hh;
        dl[o] = f2bf(v - bf2f(hh));
      }
    }
  } else {  // V -> transposed [B,H,HD,S]
#pragma unroll
    for (int nf = 0; nf < 4; ++nf) {
      const int hd = 16 * nf + j;
      const float bv = bias[col0 + hd];
      const int tok0 = row0 + 16 * w + 4 * g;
      const int bb = tok0 >> 11, ss = tok0 & 2047;
      const float v0 = acc[nf][0] + bv, v1 = acc[nf][1] + bv;
      const float v2 = acc[nf][2] + bv, v3 = acc[nf][3] + bv;
      const unsigned short h0 = f2bf(v0), h1 = f2bf(v1), h2 = f2bf(v2),
                           h3 = f2bf(v3);
      const size_t o = (((size_t)bb * H + h) * HD + hd) * S + ss;
      u2 ph, pl;
      ph.x = (unsigned)h0 | ((unsigned)h1 << 16);
      ph.y = (unsigned)h2 | ((unsigned)h3 << 16);
      pl.x = (unsigned)f2bf(v0 - bf2f(h0)) | ((unsigned)f2bf(v1 - bf2f(h1)) << 16);
      pl.y = (unsigned)f2bf(v2 - bf2f(h2)) | ((unsigned)f2bf(v3 - bf2f(h3)) << 16);
      *(u2*)(Vh + o) = ph;
      *(u2*)(Vl + o) = pl;
    }
  }
}

// ---------------------------------------------------------------------------
// Fused flash attention ctx (swapped QK^T, online softmax, PV). Writes ctx
// split bf16 [token][D] and per-row m,l for the weights kernel.
// ---------------------------------------------------------------------------
__global__ __launch_bounds__(256) void k_ctx(
    const unsigned short* __restrict__ Qh, const unsigned short* __restrict__ Ql,
    const unsigned short* __restrict__ Kh, const unsigned short* __restrict__ Kl,
    const unsigned short* __restrict__ Vh, const unsigned short* __restrict__ Vl,
    unsigned short* __restrict__ ch, unsigned short* __restrict__ cl,
    float* __restrict__ mo, float* __restrict__ lo) {
  __shared__ unsigned short Ksh[4096], Ksl[4096], Vsh[4096], Vsl[4096];
  const int tid = threadIdx.x;
  const int w = tid >> 6, lane = tid & 63;
  const int j = lane & 15, g = lane >> 4;
  const int q0 = blockIdx.x * 64;
  const int h = blockIdx.y, b = blockIdx.z;
  const size_t hb = (size_t)b * H + h;
  const int qrow = q0 + 16 * w + j;  // this lane's q (B-operand column)

  bf16x8 qfh[2], qfl[2];
#pragma unroll
  for (int kk = 0; kk < 2; ++kk) {
    const size_t o = (hb * S + qrow) * HD + kk * 32 + 8 * g;
    U16x8 u;
    u.q = *(const u4*)(Qh + o);
    qfh[kk] = u.b;
    u.q = *(const u4*)(Ql + o);
    qfl[kk] = u.b;
  }

  const f32x4 z4 = {0.f, 0.f, 0.f, 0.f};
  f32x4 ctxa[4] = {z4, z4, z4, z4};
  float m_run = -INFINITY, l_run = 0.f;

  for (int k0 = 0; k0 < S; k0 += 64) {
    __syncthreads();
    stage64(Kh, (hb * S + k0) * HD, HD, Ksh, tid);
    stage64(Kl, (hb * S + k0) * HD, HD, Ksl, tid);
    stage64(Vh, hb * HD * S + k0, S, Vsh, tid);
    stage64(Vl, hb * HD * S + k0, S, Vsl, tid);
    __syncthreads();

    // S^T[key][q] = K * Q^T  (3-term split)
    f32x4 st[4] = {z4, z4, z4, z4};
#pragma unroll
    for (int kk = 0; kk < 2; ++kk) {
#pragma unroll
      for (int kb = 0; kb < 4; ++kb) {
        const bf16x8 ah = ld_frag(Ksh, 16 * kb + j, kk * 4 + g);
        const bf16x8 al = ld_frag(Ksl, 16 * kb + j, kk * 4 + g);
        st[kb] = MM(ah, qfh[kk], st[kb]);
        st[kb] = MM(ah, qfl[kk], st[kb]);
        st[kb] = MM(al, qfh[kk], st[kb]);
      }
    }

    // online softmax: lane owns q=j; its 16 values are keys 16*kb+4*g+r
    float pm = -INFINITY;
#pragma unroll
    for (int kb = 0; kb < 4; ++kb)
#pragma unroll
      for (int r = 0; r < 4; ++r) pm = fmaxf(pm, st[kb][r]);
    pm = fmaxf(pm, __shfl_xor(pm, 16));
    pm = fmaxf(pm, __shfl_xor(pm, 32));
    const float m_new = fmaxf(m_run, pm);
    const float sc = __expf(m_run - m_new);
    m_run = m_new;
    float p[4][4];
    float ls = 0.f;
#pragma unroll
    for (int kb = 0; kb < 4; ++kb)
#pragma unroll
      for (int r = 0; r < 4; ++r) {
        p[kb][r] = __expf(st[kb][r] - m_new);
        ls += p[kb][r];
      }
    l_run = l_run * sc + ls;
#pragma unroll
    for (int mf = 0; mf < 4; ++mf) ctxa[mf] *= sc;

    // pack P (hi/lo) into u32 words: ph[kb][0]=(r0,r1), [1]=(r2,r3)
    unsigned ph[4][2], pl[4][2];
#pragma unroll
    for (int kb = 0; kb < 4; ++kb) {
      const unsigned short a0 = f2bf(p[kb][0]), a1 = f2bf(p[kb][1]);
      const unsigned short a2 = f2bf(p[kb][2]), a3 = f2bf(p[kb][3]);
      ph[kb][0] = (unsigned)a0 | ((unsigned)a1 << 16);
      ph[kb][1] = (unsigned)a2 | ((unsigned)a3 << 16);
      pl[kb][0] = (unsigned)f2bf(p[kb][0] - bf2f(a0)) |
                  ((unsigned)f2bf(p[kb][1] - bf2f(a1)) << 16);
      pl[kb][1] = (unsigned)f2bf(p[kb][2] - bf2f(a2)) |
                  ((unsigned)f2bf(p[kb][3] - bf2f(a3)) << 16);
    }

    // Redistribute P to PV B-operand slots. Lane (g,j), step t needs keys
    // 32t+8g+b: b=0..3 from lane Ga=2*(g&1), b=4..7 from Gb=Ga+1, kb=2t+(g>>1).
    const int srcA = ((g & 1) << 5) + j;
    const int srcB = srcA + 16;
    const bool hikb = (g >> 1) != 0;
#pragma unroll
    for (int t = 0; t < 2; ++t) {
      const unsigned w0a = __shfl(ph[2 * t][0], srcA), w0b = __shfl(ph[2 * t + 1][0], srcA);
      const unsigned w1a = __shfl(ph[2 * t][1], srcA), w1b = __shfl(ph[2 * t + 1][1], srcA);
      const unsigned w2a = __shfl(ph[2 * t][0], srcB), w2b = __shfl(ph[2 * t + 1][0], srcB);
      const unsigned w3a = __shfl(ph[2 * t][1], srcB), w3b = __shfl(ph[2 * t + 1][1], srcB);
      U16x8 pbh;
      pbh.q.x = hikb ? w0b : w0a;
      pbh.q.y = hikb ? w1b : w1a;
      pbh.q.z = hikb ? w2b : w2a;
      pbh.q.w = hikb ? w3b : w3a;
      const unsigned v0a = __shfl(pl[2 * t][0], srcA), v0b = __shfl(pl[2 * t + 1][0], srcA);
      const unsigned v1a = __shfl(pl[2 * t][1], srcA), v1b = __shfl(pl[2 * t + 1][1], srcA);
      const unsigned v2a = __shfl(pl[2 * t][0], srcB), v2b = __shfl(pl[2 * t + 1][0], srcB);
      const unsigned v3a = __shfl(pl[2 * t][1], srcB), v3b = __shfl(pl[2 * t + 1][1], srcB);
      U16x8 pbl;
      pbl.q.x = hikb ? v0b : v0a;
      pbl.q.y = hikb ? v1b : v1a;
      pbl.q.z = hikb ? v2b : v2a;
      pbl.q.w = hikb ? v3b : v3a;
#pragma unroll
      for (int mf = 0; mf < 4; ++mf) {
        const bf16x8 vh_ = ld_frag(Vsh, 16 * mf + j, t * 4 + g);
        const bf16x8 vl_ = ld_frag(Vsl, 16 * mf + j, t * 4 + g);
        ctxa[mf] = MM(vh_, pbh.b, ctxa[mf]);
        ctxa[mf] = MM(vh_, pbl.b, ctxa[mf]);
        ctxa[mf] = MM(vl_, pbh.b, ctxa[mf]);
      }
    }
  }

  float lt = l_run;
  lt += __shfl_xor(lt, 16);
  lt += __shfl_xor(lt, 32);
  const float inv = 1.0f / lt;
  const int tokg = b * S + (q0 + 16 * w + j);
#pragma unroll
  for (int mf = 0; mf < 4; ++mf) {
    const int feat = h * HD + 16 * mf + 4 * g;
    const float v0 = ctxa[mf][0] * inv, v1 = ctxa[mf][1] * inv;
    const float v2 = ctxa[mf][2] * inv, v3 = ctxa[mf][3] * inv;
    const unsigned short h0 = f2bf(v0), h1 = f2bf(v1), h2 = f2bf(v2),
                         h3 = f2bf(v3);
    const size_t o = (size_t)tokg * D + feat;
    u2 hh, ll;
    hh.x = (unsigned)h0 | ((unsigned)h1 << 16);
    hh.y = (unsigned)h2 | ((unsigned)h3 << 16);
    ll.x = (unsigned)f2bf(v0 - bf2f(h0)) | ((unsigned)f2bf(v1 - bf2f(h1)) << 16);
    ll.y = (unsigned)f2bf(v2 - bf2f(h2)) | ((unsigned)f2bf(v3 - bf2f(h3)) << 16);
    *(u2*)(ch + o) = hh;
    *(u2*)(cl + o) = ll;
  }
  if (g == 0) {
    mo[hb * S + qrow] = m_run;
    lo[hb * S + qrow] = lt;
  }
}

// ---------------------------------------------------------------------------
// Out projection + bias + residual (MFMA split). y = ctx @ Wout^T + b + x
// ---------------------------------------------------------------------------
__global__ __launch_bounds__(256) void k_oproj(
    const unsigned short* __restrict__ ah_, const unsigned short* __restrict__ al_,
    const unsigned short* __restrict__ wh, const unsigned short* __restrict__ wl,
    const float* __restrict__ bias, const float* __restrict__ x,
    float* __restrict__ y) {
  __shared__ unsigned short Ah[4096], Al[4096], Bh[4096], Bl[4096];
  const int tid = threadIdx.x;
  const int w = tid >> 6, lane = tid & 63;
  const int j = lane & 15, g = lane >> 4;
  const int row0 = blockIdx.y * 64;
  const int col0 = blockIdx.x * 64;
  const f32x4 z4 = {0.f, 0.f, 0.f, 0.f};
  f32x4 acc[4] = {z4, z4, z4, z4};

  for (int k0 = 0; k0 < D; k0 += 64) {
    __syncthreads();
    stage64(ah_, (size_t)row0 * D + k0, D, Ah, tid);
    stage64(al_, (size_t)row0 * D + k0, D, Al, tid);
    stage64(wh, (size_t)col0 * D + k0, D, Bh, tid);
    stage64(wl, (size_t)col0 * D + k0, D, Bl, tid);
    __syncthreads();
#pragma unroll
    for (int kk = 0; kk < 2; ++kk) {
      const int arow = 16 * w + j;
      const bf16x8 ah = ld_frag(Ah, arow, kk * 4 + g);
      const bf16x8 al = ld_frag(Al, arow, kk * 4 + g);
#pragma unroll
      for (int nf = 0; nf < 4; ++nf) {
        const bf16x8 bh = ld_frag(Bh, 16 * nf + j, kk * 4 + g);
        const bf16x8 bl = ld_frag(Bl, 16 * nf + j, kk * 4 + g);
        acc[nf] = MM(ah, bh, acc[nf]);
        acc[nf] = MM(ah, bl, acc[nf]);
        acc[nf] = MM(al, bh, acc[nf]);
      }
    }
  }
#pragma unroll
  for (int nf = 0; nf < 4; ++nf) {
    const int col = col0 + 16 * nf + j;
    const float bv = bias[col];
#pragma unroll
    for (int r = 0; r < 4; ++r) {
      const int tok = row0 + 16 * w + 4 * g + r;
      const size_t off = (size_t)tok * D + col;
      y[off] = acc[nf][r] + bv + x[off];
    }
  }
}

// ---------------------------------------------------------------------------
// attn weights: mean over heads of exp(S - m)/l.  Non-swapped QK^T.
// ---------------------------------------------------------------------------
__global__ __launch_bounds__(256) void k_wts(
    const unsigned short* __restrict__ Qh, const unsigned short* __restrict__ Ql,
    const unsigned short* __restrict__ Kh, const unsigned short* __restrict__ Kl,
    const float* __restrict__ mi, const float* __restrict__ li,
    float* __restrict__ attn) {
  __shared__ unsigned short Ksh[4096], Ksl[4096];
  const int tid = threadIdx.x;
  const int w = tid >> 6, lane = tid & 63;
  const int j = lane & 15, g = lane >> 4;
  const int k0 = blockIdx.x * 64;
  const int q0 = blockIdx.y * 64;
  const int b = blockIdx.z;
  const f32x4 z4 = {0.f, 0.f, 0.f, 0.f};
  f32x4 wacc[4] = {z4, z4, z4, z4};

  for (int h = 0; h < H; ++h) {
    const size_t hb = (size_t)b * H + h;
    __syncthreads();
    stage64(Kh, (hb * S + k0) * HD, HD, Ksh, tid);
    stage64(Kl, (hb * S + k0) * HD, HD, Ksl, tid);
    __syncthreads();
    bf16x8 qfh[2], qfl[2];
#pragma unroll
    for (int kk = 0; kk < 2; ++kk) {
      const size_t o = (hb * S + q0 + 16 * w + j) * HD + kk * 32 + 8 * g;
      U16x8 u;
      u.q = *(const u4*)(Qh + o);
      qfh[kk] = u.b;
      u.q = *(const u4*)(Ql + o);
      qfl[kk] = u.b;
    }
    f32x4 sacc[4] = {z4, z4, z4, z4};
#pragma unroll
    for (int kk = 0; kk < 2; ++kk) {
#pragma unroll
      for (int nf = 0; nf < 4; ++nf) {
        const bf16x8 kh_ = ld_frag(Ksh, 16 * nf + j, kk * 4 + g);
        const bf16x8 kl_ = ld_frag(Ksl, 16 * nf + j, kk * 4 + g);
        sacc[nf] = MM(qfh[kk], kh_, sacc[nf]);
        sacc[nf] = MM(qfh[kk], kl_, sacc[nf]);
        sacc[nf] = MM(qfl[kk], kh_, sacc[nf]);
      }
    }
    float mr[4], lv[4];
#pragma unroll
    for (int r = 0; r < 4; ++r) {
      const size_t o = hb * S + q0 + 16 * w + 4 * g + r;
      mr[r] = mi[o];
      lv[r] = 1.0f / li[o];
    }
#pragma unroll
    for (int nf = 0; nf < 4; ++nf)
#pragma unroll
      for (int r = 0; r < 4; ++r)
        wacc[nf][r] = fmaf(__expf(sacc[nf][r] - mr[r]), lv[r], wacc[nf][r]);
  }
  const float ih = 1.0f / (float)H;
#pragma unroll
  for (int nf = 0; nf < 4; ++nf)
#pragma unroll
    for (int r = 0; r < 4; ++r) {
      const size_t row = (size_t)b * S + q0 + 16 * w + 4 * g + r;
      attn[row * S + k0 + 16 * nf + j] = wacc[nf][r] * ih;
    }
}

// ---------------------------------------------------------------------------
// In-place LayerNorm (one block per row).
// ---------------------------------------------------------------------------
__global__ __launch_bounds__(256) void k_ln(float* __restrict__ y,
                                            const float* __restrict__ gamma,
                                            const float* __restrict__ beta) {
  const int row = blockIdx.x;
  const int tid = threadIdx.x;
  const float4 v = *reinterpret_cast<const float4*>(&y[(size_t)row * D + tid * 4]);
  float s = v.x + v.y + v.z + v.w;
  float sq = v.x * v.x + v.y * v.y + v.z * v.z + v.w * v.w;
#pragma unroll
  for (int off = 32; off > 0; off >>= 1) {
    s += __shfl_down(s, off);
    sq += __shfl_down(sq, off);
  }
  __shared__ float sm[8];
  const int wid = tid >> 6, lane = tid & 63;
  if (lane == 0) {
    sm[wid] = s;
    sm[4 + wid] = sq;
  }
  __syncthreads();
  s = sm[0] + sm[1] + sm[2] + sm[3];
  sq = sm[4] + sm[5] + sm[6] + sm[7];
  const float mu = s * (1.0f / D);
  const float var = sq * (1.0f / D) - mu * mu;
  const float rstd = rsqrtf(var + EPS);
  const float4 gmv = *reinterpret_cast<const float4*>(&gamma[tid * 4]);
  const float4 btv = *reinterpret_cast<const float4*>(&beta[tid * 4]);
  float4 o;
  o.x = (v.x - mu) * rstd * gmv.x + btv.x;
  o.y = (v.y - mu) * rstd * gmv.y + btv.y;
  o.z = (v.z - mu) * rstd * gmv.z + btv.z;
  o.w = (v.w - mu) * rstd * gmv.w + btv.w;
  *reinterpret_cast<float4*>(&y[(size_t)row * D + tid * 4]) = o;
}

// ---------------------------------------------------------------------------
extern "C" void kernel_launch(void* const* d_in, const int* in_sizes, int n_in,
                              void* d_out, int out_size, void* d_ws,
                              size_t ws_size, hipStream_t stream) {
  const float* x = (const float*)d_in[0];
  const float* inW = (const float*)d_in[1];
  const float* inB = (const float*)d_in[2];
  const float* outW = (const float*)d_in[3];
  const float* outB = (const float*)d_in[4];
  const float* gamma = (const float*)d_in[5];
  const float* beta = (const float*)d_in[6];

  float* out = (float*)d_out;                  // [B,S,D] = 4M f32
  float* attn = out + (size_t)T * D;           // [B,S,S] = 8M f32 = 32 MiB

  // Scratch inside the attn region (fully consumed before k_wts writes attn):
  char* ab = (char*)attn;
  unsigned short* xh = (unsigned short*)(ab);
  unsigned short* xl = (unsigned short*)(ab + (8u << 20));
  unsigned short* wih = (unsigned short*)(ab + (16u << 20));
  unsigned short* wil = (unsigned short*)(ab + (22u << 20));
  unsigned short* woh = (unsigned short*)(ab + (28u << 20));
  unsigned short* wol = (unsigned short*)(ab + (30u << 20));
  unsigned short* cth = xh;  // ctx aliases x-split region (x-split dead after k_qkv)
  unsigned short* ctl = xl;

  char* wsb = (char*)d_ws;  // 48.5 MiB used (same as round-1 footprint)
  unsigned short* Qh = (unsigned short*)(wsb);
  unsigned short* Ql = (unsigned short*)(wsb + (8u << 20));
  unsigned short* Kh = (unsigned short*)(wsb + (16u << 20));
  unsigned short* Kl = (unsigned short*)(wsb + (24u << 20));
  unsigned short* Vh = (unsigned short*)(wsb + (32u << 20));
  unsigned short* Vl = (unsigned short*)(wsb + (40u << 20));
  float* mo = (float*)(wsb + (48u << 20));
  float* lo = (float*)(wsb + (48u << 20) + 262144);

  k_split<<<4096, 256, 0, stream>>>(x, xh, xl, T * D / 4);
  k_split<<<3072, 256, 0, stream>>>(inW, wih, wil, 3 * D * D / 4);
  k_split<<<1024, 256, 0, stream>>>(outW, woh, wol, D * D / 4);
  k_qkv<<<dim3(48, 64), 256, 0, stream>>>(xh, xl, wih, wil, inB, Qh, Ql, Kh,
                                          Kl, Vh, Vl);
  k_ctx<<<dim3(32, 16, 2), 256, 0, stream>>>(Qh, Ql, Kh, Kl, Vh, Vl, cth, ctl,
                                             mo, lo);
  k_oproj<<<dim3(16, 64), 256, 0, stream>>>(cth, ctl, woh, wol, outB, x, out);
  k_wts<<<dim3(32, 32, 2), 256, 0, stream>>>(Qh, Ql, Kh, Kl, mo, lo, attn);
  k_ln<<<T, 256, 0, stream>>>(out, gamma, beta);
}

// Round 4
// 458.933 us; speedup vs baseline: 3.5263x; 1.2167x over previous
//
#include <hip/hip_runtime.h>
#include <math.h>

constexpr int B = 2, S = 2048, D = 1024, H = 16, HD = 64;
constexpr int T = B * S;  // 4096 tokens
constexpr float EPS = 1e-5f;
constexpr float LOG2E = 1.44269504088896340736f;

typedef float f32x4 __attribute__((ext_vector_type(4)));
typedef __bf16 bf16x8 __attribute__((ext_vector_type(8)));
typedef unsigned short u16;

struct alignas(16) u4 { unsigned x, y, z, w; };
struct alignas(8) u2 { unsigned x, y; };

__device__ __forceinline__ u16 f2bf(float f) {
  union { __bf16 h; u16 u; } c;
  c.h = (__bf16)f;  // native RNE convert
  return c.u;
}
__device__ __forceinline__ float bf2f(u16 h) {
  return __uint_as_float(((unsigned)h) << 16);
}
__device__ __forceinline__ unsigned pk2(float a, float b) {
  return (unsigned)f2bf(a) | ((unsigned)f2bf(b) << 16);
}
// 2^x via the native transcendental (inputs are <= 0 here; no range fixup).
__device__ __forceinline__ float fexp2(float x) {
  float r;
  asm("v_exp_f32 %0, %1" : "=v"(r) : "v"(x));
  return r;
}
__device__ __forceinline__ f32x4 MM(bf16x8 a, bf16x8 b, f32x4 c) {
  return __builtin_amdgcn_mfma_f32_16x16x32_bf16(a, b, c, 0, 0, 0);
}
union U16x8 { u4 q; bf16x8 b; };

// Read one MFMA fragment (8 contiguous k-elems) from a swizzled LDS tile.
// Tile layout: 16B chunk (r,c) stored at byte r*128 + ((c ^ (r&7))*16).
__device__ __forceinline__ bf16x8 ld_frag(const u16* lds, int row, int chunk) {
  U16x8 u;
  u.q = *(const u4*)((const char*)lds + row * 128 + ((chunk ^ (row & 7)) * 16));
  return u.b;
}

// Async-stage ITERS*256 slots of 8 u16 (= ITERS*32 rows of 64 u16).
// Linear LDS destination (conflict-free DMA write), with the XOR swizzle
// applied to the per-lane GLOBAL source address so ld_frag's layout holds
// (m173 pattern).  rows = ITERS*32, row stride = rstride u16.
template <int ITERS>
__device__ __forceinline__ void stageT(const u16* __restrict__ src, size_t off,
                                       int rstride, u16* lds, int tid) {
  const int lane = tid & 63, w = tid >> 6;
#pragma unroll
  for (int p = 0; p < ITERS; ++p) {
    const int idx = p * 256 + w * 64 + lane;
    const int r = idx >> 3, cc = idx & 7;
    const u16* gp = src + off + (size_t)r * rstride + ((cc ^ (r & 7)) * 8);
    u16* lp = lds + (size_t)(p * 256 + w * 64) * 8;  // wave-uniform base
    __builtin_amdgcn_global_load_lds(
        (const __attribute__((address_space(1))) void*)gp,
        (__attribute__((address_space(3))) void*)lp, 16, 0, 0);
  }
}

// ---------------------------------------------------------------------------
// Split fp32 -> bf16 hi + bf16 lo
// ---------------------------------------------------------------------------
__global__ __launch_bounds__(256) void k_split(const float* __restrict__ src,
                                               u16* __restrict__ hi,
                                               u16* __restrict__ lo, int n4) {
  const int i = blockIdx.x * 256 + threadIdx.x;
  if (i >= n4) return;
  const float4 v = ((const float4*)src)[i];
  u2 hh, ll;
  hh.x = pk2(v.x, v.y);
  hh.y = pk2(v.z, v.w);
  ll.x = pk2(v.x - bf2f((u16)hh.x), v.y - bf2f((u16)(hh.x >> 16)));
  ll.y = pk2(v.z - bf2f((u16)hh.y), v.w - bf2f((u16)(hh.y >> 16)));
  ((u2*)hi)[i] = hh;
  ((u2*)lo)[i] = ll;
}

// ---------------------------------------------------------------------------
// QKV projection: 128x128 tile, BK=64, 4 waves (2x2), 3-term split MFMA.
// Q pre-scaled by (1/8)*log2(e)  (scores land in base-2 domain).
// V written transposed [B,H,HD,S].
// ---------------------------------------------------------------------------
__global__ __launch_bounds__(256, 2) void k_qkv(
    const u16* __restrict__ xh, const u16* __restrict__ xl,
    const u16* __restrict__ wh, const u16* __restrict__ wl,
    const float* __restrict__ bias, u16* __restrict__ Qh, u16* __restrict__ Ql,
    u16* __restrict__ Kh, u16* __restrict__ Kl, u16* __restrict__ Vh,
    u16* __restrict__ Vl) {
  __shared__ u16 Ah[8192], Al[8192], Bh[8192], Bl[8192];
  const int tid = threadIdx.x;
  const int w = tid >> 6, lane = tid & 63;
  const int j = lane & 15, g = lane >> 4;
  const int wr = w >> 1, wc = w & 1;
  const int row0 = blockIdx.y * 128;
  const int col0 = blockIdx.x * 128;
  const f32x4 z4 = {0.f, 0.f, 0.f, 0.f};
  f32x4 acc[4][4];
#pragma unroll
  for (int mi = 0; mi < 4; ++mi)
#pragma unroll
    for (int ni = 0; ni < 4; ++ni) acc[mi][ni] = z4;

  for (int k0 = 0; k0 < D; k0 += 64) {
    __syncthreads();
    stageT<4>(xh, (size_t)row0 * D + k0, D, Ah, tid);
    stageT<4>(xl, (size_t)row0 * D + k0, D, Al, tid);
    stageT<4>(wh, (size_t)col0 * D + k0, D, Bh, tid);
    stageT<4>(wl, (size_t)col0 * D + k0, D, Bl, tid);
    __syncthreads();
#pragma unroll
    for (int kk = 0; kk < 2; ++kk) {
      bf16x8 afh[4], afl[4], bfh[4], bfl[4];
#pragma unroll
      for (int mi = 0; mi < 4; ++mi) {
        afh[mi] = ld_frag(Ah, wr * 64 + 16 * mi + j, kk * 4 + g);
        afl[mi] = ld_frag(Al, wr * 64 + 16 * mi + j, kk * 4 + g);
      }
#pragma unroll
      for (int ni = 0; ni < 4; ++ni) {
        bfh[ni] = ld_frag(Bh, wc * 64 + 16 * ni + j, kk * 4 + g);
        bfl[ni] = ld_frag(Bl, wc * 64 + 16 * ni + j, kk * 4 + g);
      }
#pragma unroll
      for (int mi = 0; mi < 4; ++mi)
#pragma unroll
        for (int ni = 0; ni < 4; ++ni) {
          acc[mi][ni] = MM(afh[mi], bfh[ni], acc[mi][ni]);
          acc[mi][ni] = MM(afh[mi], bfl[ni], acc[mi][ni]);
          acc[mi][ni] = MM(afl[mi], bfh[ni], acc[mi][ni]);
        }
    }
  }

  const int part = col0 >> 10;  // uniform per block (128 | 1024)
  if (part < 2) {
    const float qsc = (part == 0) ? 0.125f * LOG2E : 1.0f;
    u16* dh = (part == 0) ? Qh : Kh;
    u16* dl = (part == 0) ? Ql : Kl;
#pragma unroll
    for (int ni = 0; ni < 4; ++ni) {
      const int col = col0 + wc * 64 + 16 * ni + j;
      const int h = (col & 1023) >> 6, hd = col & 63;
      const float bv = bias[col];
#pragma unroll
      for (int mi = 0; mi < 4; ++mi)
#pragma unroll
        for (int r = 0; r < 4; ++r) {
          const int tok = row0 + wr * 64 + 16 * mi + 4 * g + r;
          const int bb = tok >> 11, ss = tok & 2047;
          const float v = (acc[mi][ni][r] + bv) * qsc;
          const size_t o = (((size_t)bb * H + h) * S + ss) * HD + hd;
          const u16 hv = f2bf(v);
          dh[o] = hv;
          dl[o] = f2bf(v - bf2f(hv));
        }
    }
  } else {  // V -> [B,H,HD,S]
#pragma unroll
    for (int ni = 0; ni < 4; ++ni) {
      const int col = col0 + wc * 64 + 16 * ni + j;
      const int h = (col & 1023) >> 6, hd = col & 63;
      const float bv = bias[col];
#pragma unroll
      for (int mi = 0; mi < 4; ++mi) {
        const int tok0 = row0 + wr * 64 + 16 * mi + 4 * g;
        const int bb = tok0 >> 11, ss = tok0 & 2047;
        const float v0 = acc[mi][ni][0] + bv, v1 = acc[mi][ni][1] + bv;
        const float v2 = acc[mi][ni][2] + bv, v3 = acc[mi][ni][3] + bv;
        const u16 h0 = f2bf(v0), h1 = f2bf(v1), h2 = f2bf(v2), h3 = f2bf(v3);
        const size_t o = (((size_t)bb * H + h) * HD + hd) * S + ss;
        u2 ph, pl;
        ph.x = (unsigned)h0 | ((unsigned)h1 << 16);
        ph.y = (unsigned)h2 | ((unsigned)h3 << 16);
        pl.x = pk2(v0 - bf2f(h0), v1 - bf2f(h1));
        pl.y = pk2(v2 - bf2f(h2), v3 - bf2f(h3));
        *(u2*)(Vh + o) = ph;
        *(u2*)(Vl + o) = pl;
      }
    }
  }
}

// ---------------------------------------------------------------------------
// Fused flash ctx: QBLK=128 (each wave: 2 sets of 16 q-rows), KVBLK=64.
// Swapped QK^T; online softmax in base-2 domain; in-register P redistribution.
// Outputs ctx split bf16 and (m, 1/l).
// ---------------------------------------------------------------------------
__global__ __launch_bounds__(256, 2) void k_ctx(
    const u16* __restrict__ Qh, const u16* __restrict__ Ql,
    const u16* __restrict__ Kh, const u16* __restrict__ Kl,
    const u16* __restrict__ Vh, const u16* __restrict__ Vl,
    u16* __restrict__ ch, u16* __restrict__ cl, float* __restrict__ mo,
    float* __restrict__ lo) {
  __shared__ u16 Ksh[4096], Ksl[4096], Vsh[4096], Vsl[4096];
  const int tid = threadIdx.x;
  const int w = tid >> 6, lane = tid & 63;
  const int j = lane & 15, g = lane >> 4;
  const int q0 = blockIdx.x * 128;
  const int h = blockIdx.y, b = blockIdx.z;
  const size_t hb = (size_t)b * H + h;
  int qr[2];
  qr[0] = q0 + 32 * w + j;
  qr[1] = qr[0] + 16;

  bf16x8 qfh[2][2], qfl[2][2];
#pragma unroll
  for (int s = 0; s < 2; ++s)
#pragma unroll
    for (int kk = 0; kk < 2; ++kk) {
      const size_t o = (hb * S + qr[s]) * HD + kk * 32 + 8 * g;
      U16x8 u;
      u.q = *(const u4*)(Qh + o);
      qfh[s][kk] = u.b;
      u.q = *(const u4*)(Ql + o);
      qfl[s][kk] = u.b;
    }

  const f32x4 z4 = {0.f, 0.f, 0.f, 0.f};
  f32x4 ctxa[2][4];
#pragma unroll
  for (int s = 0; s < 2; ++s)
#pragma unroll
    for (int mf = 0; mf < 4; ++mf) ctxa[s][mf] = z4;
  float m_run[2] = {-INFINITY, -INFINITY};
  float l_run[2] = {0.f, 0.f};

  for (int k0 = 0; k0 < S; k0 += 64) {
    __syncthreads();
    stageT<2>(Kh, (hb * S + k0) * HD, HD, Ksh, tid);
    stageT<2>(Kl, (hb * S + k0) * HD, HD, Ksl, tid);
    stageT<2>(Vh, hb * HD * S + k0, S, Vsh, tid);
    stageT<2>(Vl, hb * HD * S + k0, S, Vsl, tid);
    __syncthreads();

    // S^T[key][q] = K * Q^T (3-term split), for both q-sets
    f32x4 st[2][4];
#pragma unroll
    for (int s = 0; s < 2; ++s)
#pragma unroll
      for (int kb = 0; kb < 4; ++kb) st[s][kb] = z4;
#pragma unroll
    for (int kk = 0; kk < 2; ++kk) {
      bf16x8 kh4[4], kl4[4];
#pragma unroll
      for (int kb = 0; kb < 4; ++kb) {
        kh4[kb] = ld_frag(Ksh, 16 * kb + j, kk * 4 + g);
        kl4[kb] = ld_frag(Ksl, 16 * kb + j, kk * 4 + g);
      }
#pragma unroll
      for (int s = 0; s < 2; ++s)
#pragma unroll
        for (int kb = 0; kb < 4; ++kb) {
          st[s][kb] = MM(kh4[kb], qfh[s][kk], st[s][kb]);
          st[s][kb] = MM(kh4[kb], qfl[s][kk], st[s][kb]);
          st[s][kb] = MM(kl4[kb], qfh[s][kk], st[s][kb]);
        }
    }

    U16x8 pbh[2][2], pbl[2][2];
#pragma unroll
    for (int s = 0; s < 2; ++s) {
      float pm = -INFINITY;
#pragma unroll
      for (int kb = 0; kb < 4; ++kb)
#pragma unroll
        for (int r = 0; r < 4; ++r) pm = fmaxf(pm, st[s][kb][r]);
      pm = fmaxf(pm, __shfl_xor(pm, 16));
      pm = fmaxf(pm, __shfl_xor(pm, 32));
      const float m_new = fmaxf(m_run[s], pm);
      const float sc = fexp2(m_run[s] - m_new);
      m_run[s] = m_new;
      float p[4][4];
      float ls = 0.f;
#pragma unroll
      for (int kb = 0; kb < 4; ++kb)
#pragma unroll
        for (int r = 0; r < 4; ++r) {
          p[kb][r] = fexp2(st[s][kb][r] - m_new);
          ls += p[kb][r];
        }
      l_run[s] = l_run[s] * sc + ls;
#pragma unroll
      for (int mf = 0; mf < 4; ++mf) ctxa[s][mf] *= sc;

      unsigned ph[4][2], pl[4][2];
#pragma unroll
      for (int kb = 0; kb < 4; ++kb) {
        const u16 a0 = f2bf(p[kb][0]), a1 = f2bf(p[kb][1]);
        const u16 a2 = f2bf(p[kb][2]), a3 = f2bf(p[kb][3]);
        ph[kb][0] = (unsigned)a0 | ((unsigned)a1 << 16);
        ph[kb][1] = (unsigned)a2 | ((unsigned)a3 << 16);
        pl[kb][0] = pk2(p[kb][0] - bf2f(a0), p[kb][1] - bf2f(a1));
        pl[kb][1] = pk2(p[kb][2] - bf2f(a2), p[kb][3] - bf2f(a3));
      }
      // Redistribute to PV B-operand slots (verified round-2 mapping).
      const int srcA = ((g & 1) << 5) + j;
      const int srcB = srcA + 16;
      const bool hikb = (g >> 1) != 0;
#pragma unroll
      for (int t = 0; t < 2; ++t) {
        const unsigned w0a = __shfl(ph[2 * t][0], srcA),
                       w0b = __shfl(ph[2 * t + 1][0], srcA);
        const unsigned w1a = __shfl(ph[2 * t][1], srcA),
                       w1b = __shfl(ph[2 * t + 1][1], srcA);
        const unsigned w2a = __shfl(ph[2 * t][0], srcB),
                       w2b = __shfl(ph[2 * t + 1][0], srcB);
        const unsigned w3a = __shfl(ph[2 * t][1], srcB),
                       w3b = __shfl(ph[2 * t + 1][1], srcB);
        pbh[s][t].q.x = hikb ? w0b : w0a;
        pbh[s][t].q.y = hikb ? w1b : w1a;
        pbh[s][t].q.z = hikb ? w2b : w2a;
        pbh[s][t].q.w = hikb ? w3b : w3a;
        const unsigned v0a = __shfl(pl[2 * t][0], srcA),
                       v0b = __shfl(pl[2 * t + 1][0], srcA);
        const unsigned v1a = __shfl(pl[2 * t][1], srcA),
                       v1b = __shfl(pl[2 * t + 1][1], srcA);
        const unsigned v2a = __shfl(pl[2 * t][0], srcB),
                       v2b = __shfl(pl[2 * t + 1][0], srcB);
        const unsigned v3a = __shfl(pl[2 * t][1], srcB),
                       v3b = __shfl(pl[2 * t + 1][1], srcB);
        pbl[s][t].q.x = hikb ? v0b : v0a;
        pbl[s][t].q.y = hikb ? v1b : v1a;
        pbl[s][t].q.z = hikb ? v2b : v2a;
        pbl[s][t].q.w = hikb ? v3b : v3a;
      }
    }

#pragma unroll
    for (int t = 0; t < 2; ++t)
#pragma unroll
      for (int mf = 0; mf < 4; ++mf) {
        const bf16x8 vh_ = ld_frag(Vsh, 16 * mf + j, t * 4 + g);
        const bf16x8 vl_ = ld_frag(Vsl, 16 * mf + j, t * 4 + g);
#pragma unroll
        for (int s = 0; s < 2; ++s) {
          ctxa[s][mf] = MM(vh_, pbh[s][t].b, ctxa[s][mf]);
          ctxa[s][mf] = MM(vh_, pbl[s][t].b, ctxa[s][mf]);
          ctxa[s][mf] = MM(vl_, pbh[s][t].b, ctxa[s][mf]);
        }
      }
  }

#pragma unroll
  for (int s = 0; s < 2; ++s) {
    float lt = l_run[s];
    lt += __shfl_xor(lt, 16);
    lt += __shfl_xor(lt, 32);
    const float inv = 1.0f / lt;
    const int tokg = b * S + qr[s];
#pragma unroll
    for (int mf = 0; mf < 4; ++mf) {
      const int feat = h * HD + 16 * mf + 4 * g;
      const float v0 = ctxa[s][mf][0] * inv, v1 = ctxa[s][mf][1] * inv;
      const float v2 = ctxa[s][mf][2] * inv, v3 = ctxa[s][mf][3] * inv;
      const u16 h0 = f2bf(v0), h1 = f2bf(v1), h2 = f2bf(v2), h3 = f2bf(v3);
      const size_t o = (size_t)tokg * D + feat;
      u2 hh, ll;
      hh.x = (unsigned)h0 | ((unsigned)h1 << 16);
      hh.y = (unsigned)h2 | ((unsigned)h3 << 16);
      ll.x = pk2(v0 - bf2f(h0), v1 - bf2f(h1));
      ll.y = pk2(v2 - bf2f(h2), v3 - bf2f(h3));
      *(u2*)(ch + o) = hh;
      *(u2*)(cl + o) = ll;
    }
    if (g == 0) {
      mo[hb * S + qr[s]] = m_run[s];
      lo[hb * S + qr[s]] = inv;  // store 1/l
    }
  }
}

// ---------------------------------------------------------------------------
// Out projection + bias + residual: 128x128 tile, 3-term split.
// ---------------------------------------------------------------------------
__global__ __launch_bounds__(256, 2) void k_oproj(
    const u16* __restrict__ ah_, const u16* __restrict__ al_,
    const u16* __restrict__ wh, const u16* __restrict__ wl,
    const float* __restrict__ bias, const float* __restrict__ x,
    float* __restrict__ y) {
  __shared__ u16 Ah[8192], Al[8192], Bh[8192], Bl[8192];
  const int tid = threadIdx.x;
  const int w = tid >> 6, lane = tid & 63;
  const int j = lane & 15, g = lane >> 4;
  const int wr = w >> 1, wc = w & 1;
  const int row0 = blockIdx.y * 128;
  const int col0 = blockIdx.x * 128;
  const f32x4 z4 = {0.f, 0.f, 0.f, 0.f};
  f32x4 acc[4][4];
#pragma unroll
  for (int mi = 0; mi < 4; ++mi)
#pragma unroll
    for (int ni = 0; ni < 4; ++ni) acc[mi][ni] = z4;

  for (int k0 = 0; k0 < D; k0 += 64) {
    __syncthreads();
    stageT<4>(ah_, (size_t)row0 * D + k0, D, Ah, tid);
    stageT<4>(al_, (size_t)row0 * D + k0, D, Al, tid);
    stageT<4>(wh, (size_t)col0 * D + k0, D, Bh, tid);
    stageT<4>(wl, (size_t)col0 * D + k0, D, Bl, tid);
    __syncthreads();
#pragma unroll
    for (int kk = 0; kk < 2; ++kk) {
      bf16x8 afh[4], afl[4], bfh[4], bfl[4];
#pragma unroll
      for (int mi = 0; mi < 4; ++mi) {
        afh[mi] = ld_frag(Ah, wr * 64 + 16 * mi + j, kk * 4 + g);
        afl[mi] = ld_frag(Al, wr * 64 + 16 * mi + j, kk * 4 + g);
      }
#pragma unroll
      for (int ni = 0; ni < 4; ++ni) {
        bfh[ni] = ld_frag(Bh, wc * 64 + 16 * ni + j, kk * 4 + g);
        bfl[ni] = ld_frag(Bl, wc * 64 + 16 * ni + j, kk * 4 + g);
      }
#pragma unroll
      for (int mi = 0; mi < 4; ++mi)
#pragma unroll
        for (int ni = 0; ni < 4; ++ni) {
          acc[mi][ni] = MM(afh[mi], bfh[ni], acc[mi][ni]);
          acc[mi][ni] = MM(afh[mi], bfl[ni], acc[mi][ni]);
          acc[mi][ni] = MM(afl[mi], bfh[ni], acc[mi][ni]);
        }
    }
  }
#pragma unroll
  for (int ni = 0; ni < 4; ++ni) {
    const int col = col0 + wc * 64 + 16 * ni + j;
    const float bv = bias[col];
#pragma unroll
    for (int mi = 0; mi < 4; ++mi)
#pragma unroll
      for (int r = 0; r < 4; ++r) {
        const int tok = row0 + wr * 64 + 16 * mi + 4 * g + r;
        const size_t off = (size_t)tok * D + col;
        y[off] = acc[mi][ni][r] + bv + x[off];
      }
  }
}

// ---------------------------------------------------------------------------
// attn weights (mean over heads): 128q x 64k tile, 3-term split, base-2 exp.
// ---------------------------------------------------------------------------
__global__ __launch_bounds__(256, 2) void k_wts(
    const u16* __restrict__ Qh, const u16* __restrict__ Ql,
    const u16* __restrict__ Kh, const u16* __restrict__ Kl,
    const float* __restrict__ mi, const float* __restrict__ li,
    float* __restrict__ attn) {
  __shared__ u16 Ksh[4096], Ksl[4096];
  const int tid = threadIdx.x;
  const int w = tid >> 6, lane = tid & 63;
  const int j = lane & 15, g = lane >> 4;
  const int k0 = blockIdx.x * 64;
  const int q0 = blockIdx.y * 128;
  const int b = blockIdx.z;
  const f32x4 z4 = {0.f, 0.f, 0.f, 0.f};
  f32x4 wacc[2][4];
#pragma unroll
  for (int s = 0; s < 2; ++s)
#pragma unroll
    for (int nf = 0; nf < 4; ++nf) wacc[s][nf] = z4;

  for (int h = 0; h < H; ++h) {
    const size_t hb = (size_t)b * H + h;
    __syncthreads();
    stageT<2>(Kh, (hb * S + k0) * HD, HD, Ksh, tid);
    stageT<2>(Kl, (hb * S + k0) * HD, HD, Ksl, tid);
    __syncthreads();
    bf16x8 qfh[2][2], qfl[2][2];
#pragma unroll
    for (int s = 0; s < 2; ++s)
#pragma unroll
      for (int kk = 0; kk < 2; ++kk) {
        const size_t o = (hb * S + q0 + 32 * w + 16 * s + j) * HD + kk * 32 + 8 * g;
        U16x8 u;
        u.q = *(const u4*)(Qh + o);
        qfh[s][kk] = u.b;
        u.q = *(const u4*)(Ql + o);
        qfl[s][kk] = u.b;
      }
    f32x4 sacc[2][4];
#pragma unroll
    for (int s = 0; s < 2; ++s)
#pragma unroll
      for (int nf = 0; nf < 4; ++nf) sacc[s][nf] = z4;
#pragma unroll
    for (int kk = 0; kk < 2; ++kk) {
#pragma unroll
      for (int nf = 0; nf < 4; ++nf) {
        const bf16x8 kh_ = ld_frag(Ksh, 16 * nf + j, kk * 4 + g);
        const bf16x8 kl_ = ld_frag(Ksl, 16 * nf + j, kk * 4 + g);
#pragma unroll
        for (int s = 0; s < 2; ++s) {
          sacc[s][nf] = MM(qfh[s][kk], kh_, sacc[s][nf]);
          sacc[s][nf] = MM(qfh[s][kk], kl_, sacc[s][nf]);
          sacc[s][nf] = MM(qfl[s][kk], kh_, sacc[s][nf]);
        }
      }
    }
#pragma unroll
    for (int s = 0; s < 2; ++s)
#pragma unroll
      for (int r = 0; r < 4; ++r) {
        const size_t o = hb * S + q0 + 32 * w + 16 * s + 4 * g + r;
        const float m = mi[o];
        const float lv = li[o];  // already 1/l
#pragma unroll
        for (int nf = 0; nf < 4; ++nf)
          wacc[s][nf][r] = fmaf(fexp2(sacc[s][nf][r] - m), lv, wacc[s][nf][r]);
      }
  }
  const float ih = 1.0f / (float)H;
#pragma unroll
  for (int s = 0; s < 2; ++s)
#pragma unroll
    for (int nf = 0; nf < 4; ++nf)
#pragma unroll
      for (int r = 0; r < 4; ++r) {
        const size_t row = (size_t)b * S + q0 + 32 * w + 16 * s + 4 * g + r;
        attn[row * S + k0 + 16 * nf + j] = wacc[s][nf][r] * ih;
      }
}

// ---------------------------------------------------------------------------
// In-place LayerNorm (one block per row).
// ---------------------------------------------------------------------------
__global__ __launch_bounds__(256) void k_ln(float* __restrict__ y,
                                            const float* __restrict__ gamma,
                                            const float* __restrict__ beta) {
  const int row = blockIdx.x;
  const int tid = threadIdx.x;
  const float4 v = *reinterpret_cast<const float4*>(&y[(size_t)row * D + tid * 4]);
  float s = v.x + v.y + v.z + v.w;
  float sq = v.x * v.x + v.y * v.y + v.z * v.z + v.w * v.w;
#pragma unroll
  for (int off = 32; off > 0; off >>= 1) {
    s += __shfl_down(s, off);
    sq += __shfl_down(sq, off);
  }
  __shared__ float sm[8];
  const int wid = tid >> 6, lane = tid & 63;
  if (lane == 0) {
    sm[wid] = s;
    sm[4 + wid] = sq;
  }
  __syncthreads();
  s = sm[0] + sm[1] + sm[2] + sm[3];
  sq = sm[4] + sm[5] + sm[6] + sm[7];
  const float mu = s * (1.0f / D);
  const float var = sq * (1.0f / D) - mu * mu;
  const float rstd = rsqrtf(var + EPS);
  const float4 gmv = *reinterpret_cast<const float4*>(&gamma[tid * 4]);
  const float4 btv = *reinterpret_cast<const float4*>(&beta[tid * 4]);
  float4 o;
  o.x = (v.x - mu) * rstd * gmv.x + btv.x;
  o.y = (v.y - mu) * rstd * gmv.y + btv.y;
  o.z = (v.z - mu) * rstd * gmv.z + btv.z;
  o.w = (v.w - mu) * rstd * gmv.w + btv.w;
  *reinterpret_cast<float4*>(&y[(size_t)row * D + tid * 4]) = o;
}

// ---------------------------------------------------------------------------
extern "C" void kernel_launch(void* const* d_in, const int* in_sizes, int n_in,
                              void* d_out, int out_size, void* d_ws,
                              size_t ws_size, hipStream_t stream) {
  const float* x = (const float*)d_in[0];
  const float* inW = (const float*)d_in[1];
  const float* inB = (const float*)d_in[2];
  const float* outW = (const float*)d_in[3];
  const float* outB = (const float*)d_in[4];
  const float* gamma = (const float*)d_in[5];
  const float* beta = (const float*)d_in[6];

  float* out = (float*)d_out;            // [B,S,D] = 4M f32
  float* attn = out + (size_t)T * D;     // [B,S,S] = 8M f32 = 32 MiB

  // Scratch inside the attn region (fully consumed before k_wts writes attn):
  char* ab = (char*)attn;
  u16* xh = (u16*)(ab);
  u16* xl = (u16*)(ab + (8u << 20));
  u16* wih = (u16*)(ab + (16u << 20));
  u16* wil = (u16*)(ab + (22u << 20));
  u16* woh = (u16*)(ab + (28u << 20));
  u16* wol = (u16*)(ab + (30u << 20));
  u16* cth = xh;  // ctx aliases x-split region (x-split dead after k_qkv)
  u16* ctl = xl;

  char* wsb = (char*)d_ws;
  u16* Qh = (u16*)(wsb);
  u16* Ql = (u16*)(wsb + (8u << 20));
  u16* Kh = (u16*)(wsb + (16u << 20));
  u16* Kl = (u16*)(wsb + (24u << 20));
  u16* Vh = (u16*)(wsb + (32u << 20));
  u16* Vl = (u16*)(wsb + (40u << 20));
  float* mo = (float*)(wsb + (48u << 20));
  float* lo = (float*)(wsb + (48u << 20) + 262144);

  k_split<<<4096, 256, 0, stream>>>(x, xh, xl, T * D / 4);
  k_split<<<3072, 256, 0, stream>>>(inW, wih, wil, 3 * D * D / 4);
  k_split<<<1024, 256, 0, stream>>>(outW, woh, wol, D * D / 4);
  k_qkv<<<dim3(24, 32), 256, 0, stream>>>(xh, xl, wih, wil, inB, Qh, Ql, Kh,
                                          Kl, Vh, Vl);
  k_ctx<<<dim3(16, 16, 2), 256, 0, stream>>>(Qh, Ql, Kh, Kl, Vh, Vl, cth, ctl,
                                             mo, lo);
  k_oproj<<<dim3(8, 32), 256, 0, stream>>>(cth, ctl, woh, wol, outB, x, out);
  k_wts<<<dim3(32, 16, 2), 256, 0, stream>>>(Qh, Ql, Kh, Kl, mo, lo, attn);
  k_ln<<<T, 256, 0, stream>>>(out, gamma, beta);
}